// Round 12
// baseline (10044.942 us; speedup 1.0000x reference)
//
#include <hip/hip_runtime.h>

// ZoneoutGRU persistent kernel v19: B=64, T=1024, IN=512, H=1024, L=2, zo=0.1.
// 128 active blocks (64 LA, 64 LB), 256 thr (4 waves = K slices). Mailbox
// sync (v12), plain cached stream loads (v14), waves_per_eu(1,1) (v16),
// rule-#20 weight-init fix (v18: 10.2ms -> 7.7ms, -24%).
// v19 vs v18 — ONE change: per-block TILE ROTATION on the three ring streams
// (LA-h, LB-a, LB-h). rot=(blk>>3)&7 gives the 8 same-XCD sibling blocks
// (XCD = blk%8, siblings stride 8) distinct start tiles 0..7:
//   H7: the residual ~7.5us/step matches per-XCD MALL ingest of the
//   UN-DEDUPED fan-out reads (16 blocks x 256KB = 4.5MB/XCD/step @~500GB/s
//   ~= 8us). All siblings previously streamed tiles in the SAME order =>
//   simultaneous same-line misses; if those don't merge, every stream goes
//   to MALL. Rotation makes the first collective pass load each tile into
//   the XCD L2 exactly once; followers hit L2 (temporal dedup, ~8x less
//   MALL read traffic).
// Implementation: template<GL,ROT> stream + block-uniform switch => every
// weight index stays a compile-time constant (no rule-#20 regression).
// Ledger: DVFS(v8) poll(v9) depth(v10) order(v11) flaglines(v12) cache-
// under-spills(v14) null; hop=0.6us(v13); spill-chain FIXED (v18, -24%).

#define Tn 1024
#define Hn 1024
#define INn 512

typedef short s8v __attribute__((ext_vector_type(8)));
typedef float f4v __attribute__((ext_vector_type(4)));
typedef unsigned short us4v __attribute__((ext_vector_type(4)));
typedef unsigned long long ull;

// ws layout (bytes)
#define WS_XB  0u           // x bf16 [64][1024][512]            = 67,108,864
#define WS_H0R 67108864u    // ring [512][ktile64][b64][16] bf16 = 67,108,864
#define WS_H1R 134217728u   // ring [256][ktile64][b64][16] bf16 = 33,554,432
#define WS_MB  167772160u   // mailbox [8][64][64] int           =    131,072

__device__ __forceinline__ unsigned short f2bf(float f) {
  unsigned int u = __float_as_uint(f);
  u += 0x7fffu + ((u >> 16) & 1u);
  return (unsigned short)(u >> 16);
}

__device__ __forceinline__ s8v pack8(const float* p) {
  float4 a = *(const float4*)p;
  float4 b = *(const float4*)(p + 4);
  s8v r;
  r[0] = (short)f2bf(a.x); r[1] = (short)f2bf(a.y);
  r[2] = (short)f2bf(a.z); r[3] = (short)f2bf(a.w);
  r[4] = (short)f2bf(b.x); r[5] = (short)f2bf(b.y);
  r[6] = (short)f2bf(b.z); r[7] = (short)f2bf(b.w);
  return r;
}

// producer store: relaxed agent-scope 8B atomic = write-through to MALL (v3+)
__device__ __forceinline__ void st8c(unsigned short* p, us4v v) {
  union { us4v v; ull u; } c; c.v = v;
  __hip_atomic_store((ull*)p, c.u, __ATOMIC_RELAXED, __HIP_MEMORY_SCOPE_AGENT);
}

// nt store via asm: ordered against other asm/memory ops (drain-count safety)
__device__ __forceinline__ void stnt16(float* p, f4v v) {
  asm volatile("global_store_dwordx4 %0, %1, off nt" :: "v"(p), "v"(v) : "memory");
}

// consumer loads: plain cached (v14)
__device__ __forceinline__ void issue4c(s8v* f, const unsigned short* src,
                                        int kt, int w, int rl, int kg) {
#pragma unroll
  for (int m = 0; m < 4; ++m) {
    const unsigned short* p = src + (size_t)(w * 16 + kt * 2 + (kg >> 1)) * 1024
                              + (m * 16 + rl) * 16 + (kg & 1) * 8;
    asm volatile("global_load_dwordx4 %0, %1, off"
                 : "=v"(f[m]) : "v"(p) : "memory");
  }
}

template<int N> __device__ __forceinline__ void vmwait() {
  asm volatile("s_waitcnt vmcnt(%0)" :: "i"(N) : "memory");
  __builtin_amdgcn_sched_barrier(0);
}

__device__ __forceinline__ void mfma3(f4v (*acc)[4], s8v w0, s8v w1, s8v w2,
                                      const s8v f[4], const int gl) {
#pragma unroll
  for (int m = 0; m < 4; ++m) {
    acc[m][0]  = __builtin_amdgcn_mfma_f32_16x16x32_bf16(w0, f[m], acc[m][0], 0, 0, 0);
    acc[m][1]  = __builtin_amdgcn_mfma_f32_16x16x32_bf16(w1, f[m], acc[m][1], 0, 0, 0);
    acc[m][gl] = __builtin_amdgcn_mfma_f32_16x16x32_bf16(w2, f[m], acc[m][gl], 0, 0, 0);
  }
}

// v19 rotated deep-pipelined stream GEMM: consume tiles ROT, ROT+1, ... mod 8
// with MATCHING weight indices — all compile-time constants. Depth-6 ring,
// descending counted vmcnt (v10-proven). vmcnt==0 on entry; self-drains.
template<int GL, int ROT>
__device__ __forceinline__ void stream_rot(f4v (*acc)[4], const s8v (*wgt)[8],
    const unsigned short* src, int w, int rl, int kg) {
  s8v f[6][4];
#pragma unroll
  for (int i = 0; i < 6; ++i) issue4c(f[i], src, (ROT + i) & 7, w, rl, kg);
  vmwait<20>(); mfma3(acc, wgt[0][(ROT+0)&7], wgt[1][(ROT+0)&7], wgt[2][(ROT+0)&7], f[0], GL);
  issue4c(f[0], src, (ROT + 6) & 7, w, rl, kg);
  vmwait<20>(); mfma3(acc, wgt[0][(ROT+1)&7], wgt[1][(ROT+1)&7], wgt[2][(ROT+1)&7], f[1], GL);
  issue4c(f[1], src, (ROT + 7) & 7, w, rl, kg);
  vmwait<20>(); mfma3(acc, wgt[0][(ROT+2)&7], wgt[1][(ROT+2)&7], wgt[2][(ROT+2)&7], f[2], GL);
  vmwait<16>(); mfma3(acc, wgt[0][(ROT+3)&7], wgt[1][(ROT+3)&7], wgt[2][(ROT+3)&7], f[3], GL);
  vmwait<12>(); mfma3(acc, wgt[0][(ROT+4)&7], wgt[1][(ROT+4)&7], wgt[2][(ROT+4)&7], f[4], GL);
  vmwait<8>();  mfma3(acc, wgt[0][(ROT+5)&7], wgt[1][(ROT+5)&7], wgt[2][(ROT+5)&7], f[5], GL);
  vmwait<4>();  mfma3(acc, wgt[0][(ROT+6)&7], wgt[1][(ROT+6)&7], wgt[2][(ROT+6)&7], f[0], GL);
  vmwait<0>();  mfma3(acc, wgt[0][(ROT+7)&7], wgt[1][(ROT+7)&7], wgt[2][(ROT+7)&7], f[1], GL);
}

// block-uniform dispatch (rot same for all threads of a block => no diverge)
template<int GL>
__device__ __forceinline__ void stream_disp(int rot, f4v (*acc)[4],
    const s8v (*wgt)[8], const unsigned short* src, int w, int rl, int kg) {
  switch (rot) {
    case 0: stream_rot<GL, 0>(acc, wgt, src, w, rl, kg); break;
    case 1: stream_rot<GL, 1>(acc, wgt, src, w, rl, kg); break;
    case 2: stream_rot<GL, 2>(acc, wgt, src, w, rl, kg); break;
    case 3: stream_rot<GL, 3>(acc, wgt, src, w, rl, kg); break;
    case 4: stream_rot<GL, 4>(acc, wgt, src, w, rl, kg); break;
    case 5: stream_rot<GL, 5>(acc, wgt, src, w, rl, kg); break;
    case 6: stream_rot<GL, 6>(acc, wgt, src, w, rl, kg); break;
    default: stream_rot<GL, 7>(acc, wgt, src, w, rl, kg); break;
  }
}

__global__ void cvt_bf16_kernel(const float* __restrict__ src,
                                unsigned short* __restrict__ dst, int n4) {
  int i = blockIdx.x * blockDim.x + threadIdx.x;
  int st = gridDim.x * blockDim.x;
  for (; i < n4; i += st) {
    const float4 v = *(const float4*)(src + 4 * (size_t)i);
    us4v o;
    o[0] = f2bf(v.x); o[1] = f2bf(v.y); o[2] = f2bf(v.z); o[3] = f2bf(v.w);
    *(us4v*)(dst + 4 * (size_t)i) = o;
  }
}

__global__ void init_all(const float* __restrict__ h0in, char* __restrict__ ws) {
  int i = blockIdx.x * blockDim.x + threadIdx.x;   // grid 528*256 = 135168
  unsigned short* h0r = (unsigned short*)(ws + WS_H0R);
  unsigned short* h1r = (unsigned short*)(ws + WS_H1R);
  int* MB = (int*)(ws + WS_MB);
  if (i < 65536) {
    int b = i >> 10, h = i & 1023;
    int off = (h >> 4) * 1024 + b * 16 + (h & 15);
    h0r[511 * 65536 + off] = f2bf(h0in[i]);          // slot for step -1
    h1r[255 * 65536 + off] = f2bf(h0in[65536 + i]);  // slot for step -1
  }
  if (i < 32768) MB[i] = 0;                          // all mailbox groups: 0
}

// consumer wait: 64-lane gather over this block's PRIVATE mailbox rows
// (sole reader per line). row index = grp*64 + consumer; lane = producer.
__device__ __forceinline__ void mb_wait(const int* MB, int r1, int t1,
                                        int r2, int t2, int lane) {
  const int* p1 = MB + (r1 * 64 + lane);
  const int* p2 = MB + (r2 * 64 + lane);
  int tries = 0;
  for (;;) {
    int v1 = __hip_atomic_load(p1, __ATOMIC_RELAXED, __HIP_MEMORY_SCOPE_AGENT);
    int v2 = __hip_atomic_load(p2, __ATOMIC_RELAXED, __HIP_MEMORY_SCOPE_AGENT);
    if (__all(v1 >= t1 && v2 >= t2)) return;
    __builtin_amdgcn_s_sleep(1);
    if (++tries > (1 << 22)) return;   // fail visibly, never hang
  }
}

__global__ __launch_bounds__(256)
__attribute__((amdgpu_waves_per_eu(1, 1)))   // 1 wave/EU: full unified RF
void gru_persist(
    const float* __restrict__ h0in,
    const float* __restrict__ wih0, const float* __restrict__ whh0,
    const float* __restrict__ bih0, const float* __restrict__ bhh0,
    const float* __restrict__ wih1, const float* __restrict__ whh1,
    const float* __restrict__ bih1, const float* __restrict__ bhh1,
    float* __restrict__ out, char* __restrict__ ws)
{
  const unsigned short* xb = (const unsigned short*)(ws + WS_XB);
  unsigned short* h0r = (unsigned short*)(ws + WS_H0R);
  unsigned short* h1r = (unsigned short*)(ws + WS_H1R);
  int* MB = (int*)(ws + WS_MB);

  const int blk = blockIdx.x;
  const int tid = threadIdx.x;

  if (blk >= 128) {
    // busy-clock pad (insurance): NO LDS, NO barriers — each wave polls its
    // block's grp2 mailbox row every ~33k cy; exits when all LB steps done.
    const int c = blk & 63;
    float a0 = 1.0f + (float)tid * 1e-6f, a1 = a0 + 0.25f;
    float a2 = a0 + 0.5f, a3 = a0 + 0.75f;
    const float mm = 0.99999988f, cc = 1e-7f;
    int run = 1;
    for (int it = 0; it < (1 << 17) && run; ++it) {
#pragma unroll
      for (int u = 0; u < 256; ++u) {
        a0 = __builtin_fmaf(a0, mm, cc); a1 = __builtin_fmaf(a1, mm, cc);
        a2 = __builtin_fmaf(a2, mm, cc); a3 = __builtin_fmaf(a3, mm, cc);
      }
      if ((it & 15) == 0) {
        int v = __hip_atomic_load(MB + (((2 * 64) + c) * 64 + (tid & 63)),
                                  __ATOMIC_RELAXED, __HIP_MEMORY_SCOPE_AGENT);
        if (__all(v >= Tn)) run = 0;
      }
    }
    asm volatile("" :: "v"(a0), "v"(a1), "v"(a2), "v"(a3));  // keep chains live
    return;
  }

  const bool isA = blk < 64;
  const int jt = blk & 63, jj = jt * 16;
  const int w = tid >> 6;                    // wave = K-slice = owner m-group
  const int lane = tid & 63;
  const int rl = lane & 15, kg = lane >> 4;
  const int rot = (blk >> 3) & 7;            // v19: distinct per XCD-sibling

  __shared__ float cmb[4][4][64][20];        // stride 80B: conflict-free (r6)

  const int b = w * 16 + rl;                 // owner batch row (epilogue)
  const int j0 = jj + kg * 4;                // owner j base (epilogue)

  // ---- VGPR/AGPR-resident weights (v18: constant trip counts, SROA) ----
  const float* Wi = isA ? wih0 : wih1;
  const float* Wh = isA ? whh0 : whh1;
  const float* bi = isA ? bih0 : bih1;
  const float* bh = isA ? bhh0 : bhh1;
  s8v wx[3][8], wh_[3][8];
#pragma unroll
  for (int g = 0; g < 3; ++g) {
    if (isA) {
#pragma unroll
      for (int kt = 0; kt < 4; ++kt)
        wx[g][kt] = pack8(Wi + (size_t)(g * 1024 + jj + rl) * INn + w * 128 + kt * 32 + kg * 8);
    } else {
#pragma unroll
      for (int kt = 0; kt < 8; ++kt)
        wx[g][kt] = pack8(Wi + (size_t)(g * 1024 + jj + rl) * Hn + w * 256 + kt * 32 + kg * 8);
    }
#pragma unroll
    for (int kt = 0; kt < 8; ++kt)
      wh_[g][kt] = pack8(Wh + (size_t)(g * 1024 + jj + rl) * Hn + w * 256 + kt * 32 + kg * 8);
  }
  const f4v bir = *(const f4v*)(bi + j0),        bhr = *(const f4v*)(bh + j0);
  const f4v biz = *(const f4v*)(bi + 1024 + j0), bhz = *(const f4v*)(bh + 1024 + j0);
  const f4v bin = *(const f4v*)(bi + 2048 + j0), bhn = *(const f4v*)(bh + 2048 + j0);

  // ---- register-resident fp32 hidden state (this thread's (b, j0..j0+3)) ----
  f4v hv = *(const f4v*)(h0in + (isA ? 0u : 65536u) + (size_t)b * Hn + j0);

  for (int s = 0; s < Tn; ++s) {
    // 1. LA: prefetch x fragments (plain cached loads, v4-proven) before spin
    s8v bx[4][4];
    if (isA) {
#pragma unroll
      for (int m = 0; m < 4; ++m)
#pragma unroll
        for (int kt = 0; kt < 4; ++kt)
          bx[m][kt] = *(const s8v*)(xb + ((size_t)(m * 16 + rl) * Tn + s) * INn + w * 128 + kt * 32 + kg * 8);
    }
    // 2. mailbox wait (wave0 only; private rows, sole reader per line)
    if (w == 0) {
      if (isA) mb_wait(MB, 0 * 64 + jt, s,     3 * 64 + jt, s - 255, lane);
      else     mb_wait(MB, 1 * 64 + jt, s + 1, 2 * 64 + jt, s,       lane);
    }
    __syncthreads();
    vmwait<0>();                             // clean baseline for counted pipe

    f4v acc[4][4];
#pragma unroll
    for (int m = 0; m < 4; ++m)
#pragma unroll
      for (int g = 0; g < 4; ++g) acc[m][g] = (f4v){0.f, 0.f, 0.f, 0.f};

    // deep-ring slots (no address reuse within 256+ steps => cache-safe)
    const unsigned short* hsrc = isA ? (h0r + (size_t)((s - 1) & 511) * 65536)
                                     : (h1r + (size_t)((s - 1) & 255) * 65536);
    const unsigned short* asrc = h0r + (size_t)(s & 511) * 65536;  // LB input h0[s]

    if (isA) {
      // 3a. x-GEMM from registers
#pragma unroll
      for (int kt = 0; kt < 4; ++kt) {
        s8v f4[4] = { bx[0][kt], bx[1][kt], bx[2][kt], bx[3][kt] };
        mfma3(acc, wx[0][kt], wx[1][kt], wx[2][kt], f4, 2);
      }
      // 3b. hidden stream, deep-pipelined + rotated start tile
      stream_disp<3>(rot, acc, wh_, hsrc, w, rl, kg);
    } else {
      // 3. a-stream then h-stream, each deep-pipelined + rotated
      stream_disp<2>(rot, acc, wx, asrc, w, rl, kg);
      stream_disp<3>(rot, acc, wh_, hsrc, w, rl, kg);
    }

    // 4. cross-wave K-combine (LDS)
#pragma unroll
    for (int d = 0; d < 4; ++d) if (d != w)
#pragma unroll
      for (int g = 0; g < 4; ++g) *(f4v*)&cmb[d][w][lane][g * 4] = acc[d][g];
    __syncthreads();
    f4v hsum[4];
#pragma unroll
    for (int g = 0; g < 4; ++g) {
      hsum[g] = acc[w][g];
#pragma unroll
      for (int src = 0; src < 4; ++src) if (src != w) hsum[g] += *(f4v*)&cmb[w][src][lane][g * 4];
    }

    // 5. epilogue: gates + zoneout, state stays in hv registers
    us4v hb4;
#pragma unroll
    for (int rr = 0; rr < 4; ++rr) {
      float hp = hv[rr];
      float rg = 1.f / (1.f + __expf(-(hsum[0][rr] + bir[rr] + bhr[rr])));
      float zg = 1.f / (1.f + __expf(-(hsum[1][rr] + biz[rr] + bhz[rr])));
      float narg = hsum[2][rr] + bin[rr] + rg * (hsum[3][rr] + bhn[rr]);
      float e2 = __expf(2.f * narg);
      float ng = 1.f - 2.f / (e2 + 1.f);
      float nv = (1.f - zg) * ng + zg * hp;
      hv[rr] = 0.1f * hp + 0.9f * nv;
    }
    hb4[0] = f2bf(hv[0]); hb4[1] = f2bf(hv[1]); hb4[2] = f2bf(hv[2]); hb4[3] = f2bf(hv[3]);

    // 6. broadcast bf16 h (write-through 8B atomics, issued FIRST), then out
    //    nt-stores; counted drain: wait only until st8c is acked.
    if (isA) {
      st8c(h0r + (size_t)(s & 511) * 65536 + jt * 1024 + b * 16 + kg * 4, hb4);
      if (s == Tn - 1)
        stnt16(out + 67108864u + (size_t)b * Hn + j0, hv);
      vmwait<0>();                           // st8c (+final store) acked
    } else {
      st8c(h1r + (size_t)(s & 255) * 65536 + jt * 1024 + b * 16 + kg * 4, hb4);
      stnt16(out + ((size_t)b * Tn + s) * Hn + j0, hv);
      if (s == Tn - 1) {
        stnt16(out + 67108864u + 65536u + (size_t)b * Hn + j0, hv);
        vmwait<0>();
      } else {
        vmwait<1>();                         // st8c acked; out-store off-chain
      }
    }
    __syncthreads();
    // 7. flag fan-out: wave0's 64 lanes scatter (s+1) to the 64 consumer
    //    rows of each served group (plain relaxed stores, no RMW).
    if (tid < 64) {
      const int g1 = isA ? 0 : 2, g2 = isA ? 1 : 3;
      __hip_atomic_store(MB + ((g1 * 64 + tid) * 64 + jt), s + 1,
                         __ATOMIC_RELAXED, __HIP_MEMORY_SCOPE_AGENT);
      __hip_atomic_store(MB + ((g2 * 64 + tid) * 64 + jt), s + 1,
                         __ATOMIC_RELAXED, __HIP_MEMORY_SCOPE_AGENT);
    }
  }
}

extern "C" void kernel_launch(void* const* d_in, const int* in_sizes, int n_in,
                              void* d_out, int out_size, void* d_ws, size_t ws_size,
                              hipStream_t stream) {
  (void)in_sizes; (void)n_in; (void)out_size; (void)ws_size;
  const float* x    = (const float*)d_in[0];
  const float* h0in = (const float*)d_in[1];
  const float* wih0 = (const float*)d_in[2];
  const float* whh0 = (const float*)d_in[3];
  const float* bih0 = (const float*)d_in[4];
  const float* bhh0 = (const float*)d_in[5];
  const float* wih1 = (const float*)d_in[6];
  const float* whh1 = (const float*)d_in[7];
  const float* bih1 = (const float*)d_in[8];
  const float* bhh1 = (const float*)d_in[9];
  float* out = (float*)d_out;
  char* ws = (char*)d_ws;

  cvt_bf16_kernel<<<2048, 256, 0, stream>>>(x, (unsigned short*)(ws + WS_XB), 33554432 / 4);
  init_all<<<528, 256, 0, stream>>>(h0in, ws);
  gru_persist<<<dim3(256), dim3(256), 0, stream>>>(
      h0in, wih0, whh0, bih0, bhh0, wih1, whh1, bih1, bhh1, out, ws);
}

// Round 13
// 7721.887 us; speedup vs baseline: 1.3008x; 1.3008x over previous
//
#include <hip/hip_runtime.h>

// ZoneoutGRU persistent kernel v20: B=64, T=1024, IN=512, H=1024, L=2, zo=0.1.
// 128 active blocks (64 LA, 64 LB), 256 thr (4 waves = K slices). Mailbox
// sync (v12), plain cached stream loads (v14), waves_per_eu(1,1) (v16),
// rule-#20 weight-init fix (v18: 10.2 -> 7.7ms). v19 rotation REVERTED
// (regressed: 8-way instantiation ballooned spills, conflicts +75%).
// v20 vs v18 — ONE change: stream fragment ring depth 6 -> 4 (saves 32
// VGPRs/thread).
//   H8 (from cross-version counter archaeology): SQ_LDS_BANK_CONFLICT is
//   EXACTLY 7.424e8 in v8/v16/v18 — precisely the kernels whose LDS grew
//   +64KB beyond the 81,920B cmb array. That region is the compiler's
//   VGPR-spill-to-LDS block: LB frame needs ~390 regs (wx 96 + wh 96 +
//   f-ring 96 + acc 64 + biases/misc) vs the 256-VGPR cap; overflow beyond
//   AGPR-parking spills to LDS INSIDE the stream loop. Cost ~7.4e8 cycles
//   / 128 CUs ~= 40% of kernel cycles. Depth 4 keeps the proven counted-
//   vmcnt pipeline (v10 showed depth-insensitivity) and cuts the frame by
//   32 regs — the cheapest big pressure reduction.
// Verification channels: LDS_Block_Size -> 81920, SQ_LDS_BANK_CONFLICT -> 0,
// WRITE_SIZE ~1.05e6 KB. Ledger: DVFS(v8) poll(v9) depth(v10) order(v11)
// flaglines(v12) cache-under-spills(v14) rot(v19, confounded) null;
// hop=0.6us(v13); spill-chain partial fix v18 (-24%).

#define Tn 1024
#define Hn 1024
#define INn 512

typedef short s8v __attribute__((ext_vector_type(8)));
typedef float f4v __attribute__((ext_vector_type(4)));
typedef unsigned short us4v __attribute__((ext_vector_type(4)));
typedef unsigned long long ull;

// ws layout (bytes)
#define WS_XB  0u           // x bf16 [64][1024][512]            = 67,108,864
#define WS_H0R 67108864u    // ring [512][ktile64][b64][16] bf16 = 67,108,864
#define WS_H1R 134217728u   // ring [256][ktile64][b64][16] bf16 = 33,554,432
#define WS_MB  167772160u   // mailbox [8][64][64] int           =    131,072

__device__ __forceinline__ unsigned short f2bf(float f) {
  unsigned int u = __float_as_uint(f);
  u += 0x7fffu + ((u >> 16) & 1u);
  return (unsigned short)(u >> 16);
}

__device__ __forceinline__ s8v pack8(const float* p) {
  float4 a = *(const float4*)p;
  float4 b = *(const float4*)(p + 4);
  s8v r;
  r[0] = (short)f2bf(a.x); r[1] = (short)f2bf(a.y);
  r[2] = (short)f2bf(a.z); r[3] = (short)f2bf(a.w);
  r[4] = (short)f2bf(b.x); r[5] = (short)f2bf(b.y);
  r[6] = (short)f2bf(b.z); r[7] = (short)f2bf(b.w);
  return r;
}

// producer store: relaxed agent-scope 8B atomic = write-through to MALL (v3+)
__device__ __forceinline__ void st8c(unsigned short* p, us4v v) {
  union { us4v v; ull u; } c; c.v = v;
  __hip_atomic_store((ull*)p, c.u, __ATOMIC_RELAXED, __HIP_MEMORY_SCOPE_AGENT);
}

// nt store via asm: ordered against other asm/memory ops (drain-count safety)
__device__ __forceinline__ void stnt16(float* p, f4v v) {
  asm volatile("global_store_dwordx4 %0, %1, off nt" :: "v"(p), "v"(v) : "memory");
}

// consumer loads: plain cached (v14)
__device__ __forceinline__ void issue4c(s8v* f, const unsigned short* src,
                                        int kt, int w, int rl, int kg) {
#pragma unroll
  for (int m = 0; m < 4; ++m) {
    const unsigned short* p = src + (size_t)(w * 16 + kt * 2 + (kg >> 1)) * 1024
                              + (m * 16 + rl) * 16 + (kg & 1) * 8;
    asm volatile("global_load_dwordx4 %0, %1, off"
                 : "=v"(f[m]) : "v"(p) : "memory");
  }
}

template<int N> __device__ __forceinline__ void vmwait() {
  asm volatile("s_waitcnt vmcnt(%0)" :: "i"(N) : "memory");
  __builtin_amdgcn_sched_barrier(0);
}

__device__ __forceinline__ void mfma3(f4v (*acc)[4], s8v w0, s8v w1, s8v w2,
                                      const s8v f[4], const int gl) {
#pragma unroll
  for (int m = 0; m < 4; ++m) {
    acc[m][0]  = __builtin_amdgcn_mfma_f32_16x16x32_bf16(w0, f[m], acc[m][0], 0, 0, 0);
    acc[m][1]  = __builtin_amdgcn_mfma_f32_16x16x32_bf16(w1, f[m], acc[m][1], 0, 0, 0);
    acc[m][gl] = __builtin_amdgcn_mfma_f32_16x16x32_bf16(w2, f[m], acc[m][gl], 0, 0, 0);
  }
}

// v20 deep-pipelined stream GEMM, depth-4 fragment ring (16 loads in
// flight): pre-issue tiles 0..3, steady-state vmwait<12>, WAR-safe re-issue
// after consume, descending 12/8/4/0 tail. vmcnt==0 on entry; self-drains.
template<int GL>
__device__ __forceinline__ void stream_gemm_deep(f4v (*acc)[4], const s8v (*wgt)[8],
    const unsigned short* src, int w, int rl, int kg) {
  s8v f[4][4];
#pragma unroll
  for (int kt = 0; kt < 4; ++kt) issue4c(f[kt], src, kt, w, rl, kg);
  vmwait<12>(); mfma3(acc, wgt[0][0], wgt[1][0], wgt[2][0], f[0], GL);
  issue4c(f[0], src, 4, w, rl, kg);
  vmwait<12>(); mfma3(acc, wgt[0][1], wgt[1][1], wgt[2][1], f[1], GL);
  issue4c(f[1], src, 5, w, rl, kg);
  vmwait<12>(); mfma3(acc, wgt[0][2], wgt[1][2], wgt[2][2], f[2], GL);
  issue4c(f[2], src, 6, w, rl, kg);
  vmwait<12>(); mfma3(acc, wgt[0][3], wgt[1][3], wgt[2][3], f[3], GL);
  issue4c(f[3], src, 7, w, rl, kg);
  vmwait<12>(); mfma3(acc, wgt[0][4], wgt[1][4], wgt[2][4], f[0], GL);
  vmwait<8>();  mfma3(acc, wgt[0][5], wgt[1][5], wgt[2][5], f[1], GL);
  vmwait<4>();  mfma3(acc, wgt[0][6], wgt[1][6], wgt[2][6], f[2], GL);
  vmwait<0>();  mfma3(acc, wgt[0][7], wgt[1][7], wgt[2][7], f[3], GL);
}

__global__ void cvt_bf16_kernel(const float* __restrict__ src,
                                unsigned short* __restrict__ dst, int n4) {
  int i = blockIdx.x * blockDim.x + threadIdx.x;
  int st = gridDim.x * blockDim.x;
  for (; i < n4; i += st) {
    const float4 v = *(const float4*)(src + 4 * (size_t)i);
    us4v o;
    o[0] = f2bf(v.x); o[1] = f2bf(v.y); o[2] = f2bf(v.z); o[3] = f2bf(v.w);
    *(us4v*)(dst + 4 * (size_t)i) = o;
  }
}

__global__ void init_all(const float* __restrict__ h0in, char* __restrict__ ws) {
  int i = blockIdx.x * blockDim.x + threadIdx.x;   // grid 528*256 = 135168
  unsigned short* h0r = (unsigned short*)(ws + WS_H0R);
  unsigned short* h1r = (unsigned short*)(ws + WS_H1R);
  int* MB = (int*)(ws + WS_MB);
  if (i < 65536) {
    int b = i >> 10, h = i & 1023;
    int off = (h >> 4) * 1024 + b * 16 + (h & 15);
    h0r[511 * 65536 + off] = f2bf(h0in[i]);          // slot for step -1
    h1r[255 * 65536 + off] = f2bf(h0in[65536 + i]);  // slot for step -1
  }
  if (i < 32768) MB[i] = 0;                          // all mailbox groups: 0
}

// consumer wait: 64-lane gather over this block's PRIVATE mailbox rows
// (sole reader per line). row index = grp*64 + consumer; lane = producer.
__device__ __forceinline__ void mb_wait(const int* MB, int r1, int t1,
                                        int r2, int t2, int lane) {
  const int* p1 = MB + (r1 * 64 + lane);
  const int* p2 = MB + (r2 * 64 + lane);
  int tries = 0;
  for (;;) {
    int v1 = __hip_atomic_load(p1, __ATOMIC_RELAXED, __HIP_MEMORY_SCOPE_AGENT);
    int v2 = __hip_atomic_load(p2, __ATOMIC_RELAXED, __HIP_MEMORY_SCOPE_AGENT);
    if (__all(v1 >= t1 && v2 >= t2)) return;
    __builtin_amdgcn_s_sleep(1);
    if (++tries > (1 << 22)) return;   // fail visibly, never hang
  }
}

__global__ __launch_bounds__(256)
__attribute__((amdgpu_waves_per_eu(1, 1)))   // 1 wave/EU: full unified RF
void gru_persist(
    const float* __restrict__ h0in,
    const float* __restrict__ wih0, const float* __restrict__ whh0,
    const float* __restrict__ bih0, const float* __restrict__ bhh0,
    const float* __restrict__ wih1, const float* __restrict__ whh1,
    const float* __restrict__ bih1, const float* __restrict__ bhh1,
    float* __restrict__ out, char* __restrict__ ws)
{
  const unsigned short* xb = (const unsigned short*)(ws + WS_XB);
  unsigned short* h0r = (unsigned short*)(ws + WS_H0R);
  unsigned short* h1r = (unsigned short*)(ws + WS_H1R);
  int* MB = (int*)(ws + WS_MB);

  const int blk = blockIdx.x;
  const int tid = threadIdx.x;

  if (blk >= 128) {
    // busy-clock pad (insurance): NO LDS, NO barriers — each wave polls its
    // block's grp2 mailbox row every ~33k cy; exits when all LB steps done.
    const int c = blk & 63;
    float a0 = 1.0f + (float)tid * 1e-6f, a1 = a0 + 0.25f;
    float a2 = a0 + 0.5f, a3 = a0 + 0.75f;
    const float mm = 0.99999988f, cc = 1e-7f;
    int run = 1;
    for (int it = 0; it < (1 << 17) && run; ++it) {
#pragma unroll
      for (int u = 0; u < 256; ++u) {
        a0 = __builtin_fmaf(a0, mm, cc); a1 = __builtin_fmaf(a1, mm, cc);
        a2 = __builtin_fmaf(a2, mm, cc); a3 = __builtin_fmaf(a3, mm, cc);
      }
      if ((it & 15) == 0) {
        int v = __hip_atomic_load(MB + (((2 * 64) + c) * 64 + (tid & 63)),
                                  __ATOMIC_RELAXED, __HIP_MEMORY_SCOPE_AGENT);
        if (__all(v >= Tn)) run = 0;
      }
    }
    asm volatile("" :: "v"(a0), "v"(a1), "v"(a2), "v"(a3));  // keep chains live
    return;
  }

  const bool isA = blk < 64;
  const int jt = blk & 63, jj = jt * 16;
  const int w = tid >> 6;                    // wave = K-slice = owner m-group
  const int lane = tid & 63;
  const int rl = lane & 15, kg = lane >> 4;

  __shared__ float cmb[4][4][64][20];        // stride 80B: conflict-free (r6)

  const int b = w * 16 + rl;                 // owner batch row (epilogue)
  const int j0 = jj + kg * 4;                // owner j base (epilogue)

  // ---- VGPR/AGPR-resident weights (v18: constant trip counts, SROA) ----
  const float* Wi = isA ? wih0 : wih1;
  const float* Wh = isA ? whh0 : whh1;
  const float* bi = isA ? bih0 : bih1;
  const float* bh = isA ? bhh0 : bhh1;
  s8v wx[3][8], wh_[3][8];
#pragma unroll
  for (int g = 0; g < 3; ++g) {
    if (isA) {
#pragma unroll
      for (int kt = 0; kt < 4; ++kt)
        wx[g][kt] = pack8(Wi + (size_t)(g * 1024 + jj + rl) * INn + w * 128 + kt * 32 + kg * 8);
    } else {
#pragma unroll
      for (int kt = 0; kt < 8; ++kt)
        wx[g][kt] = pack8(Wi + (size_t)(g * 1024 + jj + rl) * Hn + w * 256 + kt * 32 + kg * 8);
    }
#pragma unroll
    for (int kt = 0; kt < 8; ++kt)
      wh_[g][kt] = pack8(Wh + (size_t)(g * 1024 + jj + rl) * Hn + w * 256 + kt * 32 + kg * 8);
  }
  const f4v bir = *(const f4v*)(bi + j0),        bhr = *(const f4v*)(bh + j0);
  const f4v biz = *(const f4v*)(bi + 1024 + j0), bhz = *(const f4v*)(bh + 1024 + j0);
  const f4v bin = *(const f4v*)(bi + 2048 + j0), bhn = *(const f4v*)(bh + 2048 + j0);

  // ---- register-resident fp32 hidden state (this thread's (b, j0..j0+3)) ----
  f4v hv = *(const f4v*)(h0in + (isA ? 0u : 65536u) + (size_t)b * Hn + j0);

  for (int s = 0; s < Tn; ++s) {
    // 1. LA: prefetch x fragments (plain cached loads, v4-proven) before spin
    s8v bx[4][4];
    if (isA) {
#pragma unroll
      for (int m = 0; m < 4; ++m)
#pragma unroll
        for (int kt = 0; kt < 4; ++kt)
          bx[m][kt] = *(const s8v*)(xb + ((size_t)(m * 16 + rl) * Tn + s) * INn + w * 128 + kt * 32 + kg * 8);
    }
    // 2. mailbox wait (wave0 only; private rows, sole reader per line)
    if (w == 0) {
      if (isA) mb_wait(MB, 0 * 64 + jt, s,     3 * 64 + jt, s - 255, lane);
      else     mb_wait(MB, 1 * 64 + jt, s + 1, 2 * 64 + jt, s,       lane);
    }
    __syncthreads();
    vmwait<0>();                             // clean baseline for counted pipe

    f4v acc[4][4];
#pragma unroll
    for (int m = 0; m < 4; ++m)
#pragma unroll
      for (int g = 0; g < 4; ++g) acc[m][g] = (f4v){0.f, 0.f, 0.f, 0.f};

    // deep-ring slots (no address reuse within 256+ steps => cache-safe)
    const unsigned short* hsrc = isA ? (h0r + (size_t)((s - 1) & 511) * 65536)
                                     : (h1r + (size_t)((s - 1) & 255) * 65536);
    const unsigned short* asrc = h0r + (size_t)(s & 511) * 65536;  // LB input h0[s]

    if (isA) {
      // 3a. x-GEMM from registers
#pragma unroll
      for (int kt = 0; kt < 4; ++kt) {
        s8v f4[4] = { bx[0][kt], bx[1][kt], bx[2][kt], bx[3][kt] };
        mfma3(acc, wx[0][kt], wx[1][kt], wx[2][kt], f4, 2);
      }
      // 3b. hidden stream, deep-pipelined (depth-4 ring)
      stream_gemm_deep<3>(acc, wh_, hsrc, w, rl, kg);
    } else {
      // 3. a-stream then h-stream, each deep-pipelined (self-draining)
      stream_gemm_deep<2>(acc, wx, asrc, w, rl, kg);
      stream_gemm_deep<3>(acc, wh_, hsrc, w, rl, kg);
    }

    // 4. cross-wave K-combine (LDS)
#pragma unroll
    for (int d = 0; d < 4; ++d) if (d != w)
#pragma unroll
      for (int g = 0; g < 4; ++g) *(f4v*)&cmb[d][w][lane][g * 4] = acc[d][g];
    __syncthreads();
    f4v hsum[4];
#pragma unroll
    for (int g = 0; g < 4; ++g) {
      hsum[g] = acc[w][g];
#pragma unroll
      for (int src = 0; src < 4; ++src) if (src != w) hsum[g] += *(f4v*)&cmb[w][src][lane][g * 4];
    }

    // 5. epilogue: gates + zoneout, state stays in hv registers
    us4v hb4;
#pragma unroll
    for (int rr = 0; rr < 4; ++rr) {
      float hp = hv[rr];
      float rg = 1.f / (1.f + __expf(-(hsum[0][rr] + bir[rr] + bhr[rr])));
      float zg = 1.f / (1.f + __expf(-(hsum[1][rr] + biz[rr] + bhz[rr])));
      float narg = hsum[2][rr] + bin[rr] + rg * (hsum[3][rr] + bhn[rr]);
      float e2 = __expf(2.f * narg);
      float ng = 1.f - 2.f / (e2 + 1.f);
      float nv = (1.f - zg) * ng + zg * hp;
      hv[rr] = 0.1f * hp + 0.9f * nv;
    }
    hb4[0] = f2bf(hv[0]); hb4[1] = f2bf(hv[1]); hb4[2] = f2bf(hv[2]); hb4[3] = f2bf(hv[3]);

    // 6. broadcast bf16 h (write-through 8B atomics, issued FIRST), then out
    //    nt-stores; counted drain: wait only until st8c is acked.
    if (isA) {
      st8c(h0r + (size_t)(s & 511) * 65536 + jt * 1024 + b * 16 + kg * 4, hb4);
      if (s == Tn - 1)
        stnt16(out + 67108864u + (size_t)b * Hn + j0, hv);
      vmwait<0>();                           // st8c (+final store) acked
    } else {
      st8c(h1r + (size_t)(s & 255) * 65536 + jt * 1024 + b * 16 + kg * 4, hb4);
      stnt16(out + ((size_t)b * Tn + s) * Hn + j0, hv);
      if (s == Tn - 1) {
        stnt16(out + 67108864u + 65536u + (size_t)b * Hn + j0, hv);
        vmwait<0>();
      } else {
        vmwait<1>();                         // st8c acked; out-store off-chain
      }
    }
    __syncthreads();
    // 7. flag fan-out: wave0's 64 lanes scatter (s+1) to the 64 consumer
    //    rows of each served group (plain relaxed stores, no RMW).
    if (tid < 64) {
      const int g1 = isA ? 0 : 2, g2 = isA ? 1 : 3;
      __hip_atomic_store(MB + ((g1 * 64 + tid) * 64 + jt), s + 1,
                         __ATOMIC_RELAXED, __HIP_MEMORY_SCOPE_AGENT);
      __hip_atomic_store(MB + ((g2 * 64 + tid) * 64 + jt), s + 1,
                         __ATOMIC_RELAXED, __HIP_MEMORY_SCOPE_AGENT);
    }
  }
}

extern "C" void kernel_launch(void* const* d_in, const int* in_sizes, int n_in,
                              void* d_out, int out_size, void* d_ws, size_t ws_size,
                              hipStream_t stream) {
  (void)in_sizes; (void)n_in; (void)out_size; (void)ws_size;
  const float* x    = (const float*)d_in[0];
  const float* h0in = (const float*)d_in[1];
  const float* wih0 = (const float*)d_in[2];
  const float* whh0 = (const float*)d_in[3];
  const float* bih0 = (const float*)d_in[4];
  const float* bhh0 = (const float*)d_in[5];
  const float* wih1 = (const float*)d_in[6];
  const float* whh1 = (const float*)d_in[7];
  const float* bih1 = (const float*)d_in[8];
  const float* bhh1 = (const float*)d_in[9];
  float* out = (float*)d_out;
  char* ws = (char*)d_ws;

  cvt_bf16_kernel<<<2048, 256, 0, stream>>>(x, (unsigned short*)(ws + WS_XB), 33554432 / 4);
  init_all<<<528, 256, 0, stream>>>(h0in, ws);
  gru_persist<<<dim3(256), dim3(256), 0, stream>>>(
      h0in, wih0, whh0, bih0, bhh0, wih1, whh1, bih1, bhh1, out, ws);
}